// Round 2
// baseline (2164.619 us; speedup 1.0000x reference)
//
#include <hip/hip_runtime.h>
#include <math.h>

#define NN   48    // N_NODES
#define MD   56    // MAX_DIM
#define GC1  128
#define GC2  64

// One block per batch item. 256 threads = 4 waves.
// LDS ~69KB -> 2 blocks/CU.
__global__ __launch_bounds__(256, 2)
void policy_fwd(const int* __restrict__ Nmat, const float* __restrict__ adj,
                const float* __restrict__ W1, const float* __restrict__ b1,
                const float* __restrict__ W2, const float* __restrict__ b2,
                const float* __restrict__ agg_sW, const float* __restrict__ agg_sb,
                const float* __restrict__ agg_tW, const float* __restrict__ agg_tb,
                const float* __restrict__ l1W, const float* __restrict__ l1b,
                const float* __restrict__ l2W, const float* __restrict__ l2b,
                const float* __restrict__ f1, const float* __restrict__ f2,
                const float* __restrict__ s1, const float* __restrict__ s2,
                const float* __restrict__ e1, const float* __restrict__ e2,
                const float* __restrict__ t1W, const float* __restrict__ t1b,
                const float* __restrict__ t2W, const float* __restrict__ t2b,
                const float* __restrict__ v1W, const float* __restrict__ v1b,
                const float* __restrict__ v2W, const float* __restrict__ v2b,
                const float* __restrict__ v3W, const float* __restrict__ v3b,
                float* __restrict__ out)
{
  __shared__ __align__(16) float sAT[NN*NN];   // A_sum transposed: sAT[k*48+i]
  __shared__ __align__(16) float sU1[GC1*NN];  // h1[j*128+d] -> hT[d*48+i] -> M4 partials
  __shared__ __align__(16) float sU2[4736];    // weight staging: 4096 W | 576 onehot rows | 64 bias
  __shared__ __align__(16) float sU3[NN*GC2];  // h2[i*64+d]   -> later houtT[d*48+i]
  __shared__ float sDeg[3*NN];
  __shared__ float sGsum[128];
  __shared__ float sT[640];                    // tail scratch
  __shared__ int   sNi[MD];

  const int b   = blockIdx.x;
  const int tid = threadIdx.x;
  const float* adjB = adj + (size_t)b * (3*NN*NN);

  if (tid < MD)  sNi[tid]   = Nmat[b*MD + tid];

  // ---- degree: deg[r][i] = 1/(1 + sum_j adj[r][i][j]); 16 lanes per row ----
  {
    const int lane = tid & 15, grp = tid >> 4;
    for (int p = 0; p < 9; ++p) {
      const int row = p*16 + grp;               // 0..143 = r*48+i
      const float* rp = adjB + row*NN;
      float s = rp[lane] + rp[lane+16] + rp[lane+32];
      s += __shfl_down(s, 8, 16);
      s += __shfl_down(s, 4, 16);
      s += __shfl_down(s, 2, 16);
      s += __shfl_down(s, 1, 16);
      if (lane == 0) sDeg[row] = 1.0f/(s + 1.0f);
    }
  }
  __syncthreads();

  // ---- A^T = (sum_r adj_r * deg_r)^T ; h1 = W1[node]+b1 (embedding) ----
  for (int o = tid; o < NN*NN; o += 256) {
    const int i = o / NN, j = o - i*NN;
    const float v = adjB[i*NN + j]          * sDeg[i]
                  + adjB[(NN + i)*NN + j]   * sDeg[NN + i]
                  + adjB[(2*NN + i)*NN + j] * sDeg[2*NN + i];
    sAT[j*NN + i] = v;  // second adj read hits L2 (block's 27.6KB is resident)
  }
  for (int o = tid; o < NN*GC1; o += 256) {
    const int j = o >> 7, d = o & 127;
    sU1[o] = W1[sNi[j]*GC1 + d] + b1[d];
  }
  __syncthreads();

  // ---- M1: h = tanh(A@h1 + h1), 48x128, K=48. Tile 6x4. ----
  float hreg[6][4];
  {
    const int i0 = (tid >> 5)*6, d0 = (tid & 31)*4;
    float acc[6][4] = {};
    for (int k = 0; k < NN; ++k) {
      const float* ap = &sAT[k*NN + i0];                       // broadcast-ish
      const float4 bv = *(const float4*)&sU1[k*GC1 + d0];      // uniform-k row
      #pragma unroll
      for (int ii = 0; ii < 6; ++ii) {
        const float a = ap[ii];
        acc[ii][0] = fmaf(a, bv.x, acc[ii][0]);
        acc[ii][1] = fmaf(a, bv.y, acc[ii][1]);
        acc[ii][2] = fmaf(a, bv.z, acc[ii][2]);
        acc[ii][3] = fmaf(a, bv.w, acc[ii][3]);
      }
    }
    #pragma unroll
    for (int ii = 0; ii < 6; ++ii)
      #pragma unroll
      for (int dd = 0; dd < 4; ++dd)
        hreg[ii][dd] = tanhf(acc[ii][dd] + sU1[(i0+ii)*GC1 + d0 + dd]);
  }
  __syncthreads();                    // all h1 reads done
  {
    const int i0 = (tid >> 5)*6, d0 = (tid & 31)*4;
    #pragma unroll
    for (int dd = 0; dd < 4; ++dd)
      #pragma unroll
      for (int ii = 0; ii < 6; ++ii)
        sU1[(d0+dd)*NN + i0 + ii] = hreg[ii][dd];   // hT[d][i]
  }
  for (int o = tid; o < 4096; o += 256) sU2[o] = W2[o];   // W2 rows 0..63
  __syncthreads();

  // ---- M2: h2 = h@W2 + b2, 48x64, K=128 (two staged halves). Tile 3x4. ----
  const int i02 = (tid >> 4)*3, d02 = (tid & 15)*4;
  float acc2[3][4] = {};
  for (int k = 0; k < 64; ++k) {
    const float* ap = &sU1[k*NN + i02];
    const float4 bv = *(const float4*)&sU2[k*GC2 + d02];
    #pragma unroll
    for (int ii = 0; ii < 3; ++ii) {
      const float a = ap[ii];
      acc2[ii][0] = fmaf(a, bv.x, acc2[ii][0]);
      acc2[ii][1] = fmaf(a, bv.y, acc2[ii][1]);
      acc2[ii][2] = fmaf(a, bv.z, acc2[ii][2]);
      acc2[ii][3] = fmaf(a, bv.w, acc2[ii][3]);
    }
  }
  __syncthreads();
  for (int o = tid; o < 4096; o += 256) sU2[o] = W2[4096 + o];  // rows 64..127
  __syncthreads();
  for (int k = 0; k < 64; ++k) {
    const float* ap = &sU1[(64 + k)*NN + i02];
    const float4 bv = *(const float4*)&sU2[k*GC2 + d02];
    #pragma unroll
    for (int ii = 0; ii < 3; ++ii) {
      const float a = ap[ii];
      acc2[ii][0] = fmaf(a, bv.x, acc2[ii][0]);
      acc2[ii][1] = fmaf(a, bv.y, acc2[ii][1]);
      acc2[ii][2] = fmaf(a, bv.z, acc2[ii][2]);
      acc2[ii][3] = fmaf(a, bv.w, acc2[ii][3]);
    }
  }
  #pragma unroll
  for (int ii = 0; ii < 3; ++ii)
    #pragma unroll
    for (int dd = 0; dd < 4; ++dd)
      sU3[(i02+ii)*GC2 + d02 + dd] = acc2[ii][dd] + b2[d02+dd];
  __syncthreads();

  // ---- M3: h_out = tanh(A@h2 + h2), 48x64, K=48. ----
  {
    float acc3[3][4] = {};
    for (int k = 0; k < NN; ++k) {
      const float* ap = &sAT[k*NN + i02];
      const float4 bv = *(const float4*)&sU3[k*GC2 + d02];
      #pragma unroll
      for (int ii = 0; ii < 3; ++ii) {
        const float a = ap[ii];
        acc3[ii][0] = fmaf(a, bv.x, acc3[ii][0]);
        acc3[ii][1] = fmaf(a, bv.y, acc3[ii][1]);
        acc3[ii][2] = fmaf(a, bv.z, acc3[ii][2]);
        acc3[ii][3] = fmaf(a, bv.w, acc3[ii][3]);
      }
    }
    float ho[3][4];
    #pragma unroll
    for (int ii = 0; ii < 3; ++ii)
      #pragma unroll
      for (int dd = 0; dd < 4; ++dd)
        ho[ii][dd] = tanhf(acc3[ii][dd] + sU3[(i02+ii)*GC2 + d02 + dd]);
    __syncthreads();
    #pragma unroll
    for (int dd = 0; dd < 4; ++dd)
      #pragma unroll
      for (int ii = 0; ii < 3; ++ii)
        sU3[(d02+dd)*NN + i02 + ii] = ho[ii][dd];   // houtT[d][i]
    __syncthreads();
  }

  // ---- M4: gate = sigmoid(ann@sW+sb)*tanh(ann@tW+tb); gsum = sum_i gate ----
  // onehot part of ann is a row-gather: aggW[64+node[i]][e]
  // DETERMINISTIC reduction: partials -> sU1 (dead after M2) -> fixed-order sum.
  for (int ch = 0; ch < 2; ++ch) {
    float sg[3][4];
    {
      for (int o = tid; o < 4096; o += 256) sU2[o]      = agg_sW[(o>>6)*GC1 + ch*64 + (o&63)];
      for (int o = tid; o < 576;  o += 256) sU2[4096+o] = agg_sW[(64+(o>>6))*GC1 + ch*64 + (o&63)];
      if (tid < 64) sU2[4672+tid] = agg_sb[ch*64 + tid];
      __syncthreads();
      float acc[3][4] = {};
      for (int k = 0; k < 64; ++k) {
        const float* ap = &sU3[k*NN + i02];
        const float4 bv = *(const float4*)&sU2[k*64 + d02];
        #pragma unroll
        for (int ii = 0; ii < 3; ++ii) {
          const float a = ap[ii];
          acc[ii][0] = fmaf(a, bv.x, acc[ii][0]);
          acc[ii][1] = fmaf(a, bv.y, acc[ii][1]);
          acc[ii][2] = fmaf(a, bv.z, acc[ii][2]);
          acc[ii][3] = fmaf(a, bv.w, acc[ii][3]);
        }
      }
      #pragma unroll
      for (int ii = 0; ii < 3; ++ii)
        #pragma unroll
        for (int dd = 0; dd < 4; ++dd)
          sg[ii][dd] = acc[ii][dd] + sU2[4096 + sNi[i02+ii]*64 + d02+dd] + sU2[4672 + d02+dd];
    }
    __syncthreads();
    {
      for (int o = tid; o < 4096; o += 256) sU2[o]      = agg_tW[(o>>6)*GC1 + ch*64 + (o&63)];
      for (int o = tid; o < 576;  o += 256) sU2[4096+o] = agg_tW[(64+(o>>6))*GC1 + ch*64 + (o&63)];
      if (tid < 64) sU2[4672+tid] = agg_tb[ch*64 + tid];
      __syncthreads();
      float acc[3][4] = {};
      for (int k = 0; k < 64; ++k) {
        const float* ap = &sU3[k*NN + i02];
        const float4 bv = *(const float4*)&sU2[k*64 + d02];
        #pragma unroll
        for (int ii = 0; ii < 3; ++ii) {
          const float a = ap[ii];
          acc[ii][0] = fmaf(a, bv.x, acc[ii][0]);
          acc[ii][1] = fmaf(a, bv.y, acc[ii][1]);
          acc[ii][2] = fmaf(a, bv.z, acc[ii][2]);
          acc[ii][3] = fmaf(a, bv.w, acc[ii][3]);
        }
      }
      const int grp = tid >> 4;   // 16 row-groups per column
      #pragma unroll
      for (int dd = 0; dd < 4; ++dd) {
        float part = 0.0f;
        #pragma unroll
        for (int ii = 0; ii < 3; ++ii) {
          const float tg  = acc[ii][dd] + sU2[4096 + sNi[i02+ii]*64 + d02+dd] + sU2[4672 + d02+dd];
          const float sgm = 1.0f/(1.0f + expf(-sg[ii][dd]));
          part = fmaf(sgm, tanhf(tg), part);
        }
        sU1[grp*64 + d02 + dd] = part;   // partials, fixed slot per group
      }
      __syncthreads();
      if (tid < 64) {                    // fixed-order sum over 16 groups
        float s = 0.0f;
        #pragma unroll
        for (int g = 0; g < 16; ++g) s += sU1[g*64 + tid];
        sGsum[ch*64 + tid] = s;
      }
    }
    __syncthreads();
  }

  // ---- tail MLP (per item, tiny) ----
  if (tid < 128) sT[tid] = tanhf(sGsum[tid]);          // g: sT[0..128)
  __syncthreads();
  if (tid < 128) {                                     // a1 = g@l1W+l1b: sT[128..256)
    float a = l1b[tid];
    for (int k = 0; k < 128; ++k) a = fmaf(sT[k], l1W[k*128 + tid], a);
    sT[128 + tid] = a;
  }
  __syncthreads();
  if (tid < 64) {                                      // hfeat: sT[256..320)
    float a = l2b[tid];
    for (int k = 0; k < 128; ++k) a = fmaf(sT[128+k], l2W[k*64 + tid], a);
    sT[256 + tid] = a;
  }
  __syncthreads();
  if (tid < 160) {                                     // 5 heads layer1: sT[320..480)
    const int hh = tid >> 5, j = tid & 31;
    const float* Wp = (hh==0) ? f1 : (hh==1) ? s1 : (hh==2) ? e1 : (hh==3) ? t1W : v1W;
    float a = (hh==3) ? t1b[j] : (hh==4) ? v1b[j] : 0.0f;
    for (int k = 0; k < 64; ++k) a = fmaf(sT[256+k], Wp[k*32 + j], a);
    sT[320 + tid] = (a > 0.0f) ? a : 0.1f*a;           // leaky_relu(0.1)
  }
  __syncthreads();
  if (tid < 56) {                                      // out1: sT[480..536)
    float a = 0.0f;
    for (int k = 0; k < 32; ++k) a = fmaf(sT[320+k], f2[k*56 + tid], a);
    sT[480 + tid] = a;
  } else if (tid < 112) {                              // out2: sT[536..592)
    const int m = tid - 56; float a = 0.0f;
    for (int k = 0; k < 32; ++k) a = fmaf(sT[352+k], s2[k*56 + m], a);
    sT[536 + m] = a;
  } else if (tid < 115) {                              // oute: sT[592..595)
    const int m = tid - 112; float a = 0.0f;
    for (int k = 0; k < 32; ++k) a = fmaf(sT[384+k], e2[k*3 + m], a);
    sT[592 + m] = a;
  } else if (tid < 117) {                              // outs: sT[595..597)
    const int m = tid - 115; float a = t2b[m];
    for (int k = 0; k < 32; ++k) a = fmaf(sT[416+k], t2W[k*2 + m], a);
    sT[595 + m] = a;
  } else if (tid < 133) {                              // v2h: sT[600..616)
    const int m = tid - 117; float a = v2b[m];
    for (int k = 0; k < 32; ++k) a = fmaf(sT[448+k], v2W[k*16 + m], a);
    sT[600 + m] = (a > 0.0f) ? a : 0.1f*a;
  }
  __syncthreads();
  if (tid == 0) {                                      // value: sT[616]
    float a = v3b[0];
    for (int k = 0; k < 16; ++k) a = fmaf(sT[600+k], v3W[k], a);
    sT[616] = a;
  }
  __syncthreads();

  // ---- masks + softmaxes, wave 0 ----
  if (tid < 64) {
    const int m = tid;
    const bool inb = (m < MD);
    const bool ex  = inb && (sNi[m] > 0) && (m < NN);
    const size_t ob = (size_t)b * 118;

    // p1 + first = argmax (first-index-wins on ties)
    float lg1 = inb ? (sT[480+m] + (ex ? 0.0f : -10000.0f)) : -INFINITY;
    float mv = lg1; int mi = inb ? m : 1000;
    #pragma unroll
    for (int off = 32; off > 0; off >>= 1) {
      const float ov = __shfl_down(mv, off);
      const int   oi = __shfl_down(mi, off);
      if (ov > mv || (ov == mv && oi < mi)) { mv = ov; mi = oi; }
    }
    mv = __shfl(mv, 0);
    const int first = __shfl(mi, 0);
    float ev = inb ? expf(lg1 - mv) : 0.0f;
    float sum1 = ev;
    #pragma unroll
    for (int off = 32; off > 0; off >>= 1) sum1 += __shfl_down(sum1, off);
    sum1 = __shfl(sum1, 0);
    if (inb) out[ob + m] = ev / sum1;

    // p2
    const bool m2 = inb && ((ex || m >= NN) && (m != first));
    float lg2 = inb ? (sT[536+m] + (m2 ? 0.0f : -10000.0f)) : -INFINITY;
    float mv2 = lg2;
    #pragma unroll
    for (int off = 32; off > 0; off >>= 1) mv2 = fmaxf(mv2, __shfl_down(mv2, off));
    mv2 = __shfl(mv2, 0);
    float ev2 = inb ? expf(lg2 - mv2) : 0.0f;
    float sum2 = ev2;
    #pragma unroll
    for (int off = 32; off > 0; off >>= 1) sum2 += __shfl_down(sum2, off);
    sum2 = __shfl(sum2, 0);
    if (inb) out[ob + 56 + m] = ev2 / sum2;

    if (m < 3) {
      const float x0 = sT[592], x1 = sT[593], x2 = sT[594];
      const float mx = fmaxf(x0, fmaxf(x1, x2));
      const float q0 = expf(x0-mx), q1 = expf(x1-mx), q2 = expf(x2-mx);
      out[ob + 112 + m] = ((m==0) ? q0 : (m==1) ? q1 : q2) / (q0+q1+q2);
    }
    if (m < 2) {
      const float x0 = sT[595], x1 = sT[596];
      const float mx = fmaxf(x0, x1);
      const float q0 = expf(x0-mx), q1 = expf(x1-mx);
      out[ob + 115 + m] = ((m==0) ? q0 : q1) / (q0+q1);
    }
    if (m == 0) out[ob + 117] = sT[616];
  }
}

extern "C" void kernel_launch(void* const* d_in, const int* in_sizes, int n_in,
                              void* d_out, int out_size, void* d_ws, size_t ws_size,
                              hipStream_t stream) {
  (void)n_in; (void)out_size; (void)d_ws; (void)ws_size;
  const int B = in_sizes[0] / MD;
  policy_fwd<<<dim3(B), dim3(256), 0, stream>>>(
      (const int*)d_in[0],  (const float*)d_in[1],
      (const float*)d_in[2],  (const float*)d_in[3],
      (const float*)d_in[4],  (const float*)d_in[5],
      (const float*)d_in[6],  (const float*)d_in[7],
      (const float*)d_in[8],  (const float*)d_in[9],
      (const float*)d_in[10], (const float*)d_in[11],
      (const float*)d_in[12], (const float*)d_in[13],
      (const float*)d_in[14], (const float*)d_in[15],
      (const float*)d_in[16], (const float*)d_in[17],
      (const float*)d_in[18], (const float*)d_in[19],
      (const float*)d_in[20], (const float*)d_in[21],
      (const float*)d_in[22], (const float*)d_in[23],
      (const float*)d_in[24], (const float*)d_in[25],
      (const float*)d_in[26], (const float*)d_in[27],
      (const float*)d_in[28], (const float*)d_in[29],
      (float*)d_out);
}

// Round 4
// 944.784 us; speedup vs baseline: 2.2911x; 2.2911x over previous
//
#include <hip/hip_runtime.h>
#include <math.h>

#define NN 48
#define MD 56

__device__ __forceinline__ float rcp_f(float x){
#if __has_builtin(__builtin_amdgcn_rcpf)
  return __builtin_amdgcn_rcpf(x);
#else
  return 1.0f/x;
#endif
}

// One block per batch item; 256 threads; 53.7KB LDS -> 3 blocks/CU (12 waves).
__global__ __launch_bounds__(256, 3)
void policy_fwd(const int* __restrict__ Nmat, const float* __restrict__ adj,
                const float* __restrict__ W1, const float* __restrict__ b1,
                const float* __restrict__ W2, const float* __restrict__ b2,
                const float* __restrict__ agg_sW, const float* __restrict__ agg_sb,
                const float* __restrict__ agg_tW, const float* __restrict__ agg_tb,
                const float* __restrict__ l1W, const float* __restrict__ l1b,
                const float* __restrict__ l2W, const float* __restrict__ l2b,
                const float* __restrict__ f1, const float* __restrict__ f2,
                const float* __restrict__ s1, const float* __restrict__ s2,
                const float* __restrict__ e1, const float* __restrict__ e2,
                const float* __restrict__ t1W, const float* __restrict__ t1b,
                const float* __restrict__ t2W, const float* __restrict__ t2b,
                const float* __restrict__ v1W, const float* __restrict__ v1b,
                const float* __restrict__ v2W, const float* __restrict__ v2b,
                const float* __restrict__ v3W, const float* __restrict__ v3b,
                float* __restrict__ out)
{
  __shared__ __align__(16) float sA[NN*49];     // A row-major, stride 49
  __shared__ __align__(16) float sH[NN*132];    // h then h_out, stride 132
  __shared__ __align__(16) float sH2[3264];     // h2 (48x68) -> [agg rows|biases|sT]
  __shared__ __align__(16) float sEP[1152];     // embT[9][128] -> M4 partials[16][64]
  __shared__ float sGsum[128];
  __shared__ float sDeg[144];
  __shared__ int   sNi[MD];

  const int b   = blockIdx.x;
  const int tid = threadIdx.x;
  const float* adjB = adj + (size_t)b * (3*NN*NN);

  if (tid < MD) sNi[tid] = Nmat[b*MD + tid];

  // ---- degrees: deg[r][i] = 1/(1+row_sum); 16 lanes per row (exact div) ----
  {
    const int lane = tid & 15, grp = tid >> 4;
    for (int p = 0; p < 9; ++p) {
      const int row = p*16 + grp;               // r*48+i
      const float* rp = adjB + row*NN;
      float s = rp[lane] + rp[lane+16] + rp[lane+32];
      s += __shfl_down(s, 8, 16);
      s += __shfl_down(s, 4, 16);
      s += __shfl_down(s, 2, 16);
      s += __shfl_down(s, 1, 16);
      if (lane == 0) sDeg[row] = 1.0f/(s + 1.0f);
    }
  }
  // embT[t][d] = W1[t][d] + b1[d]  (9x128)
  for (int o = tid; o < 1152; o += 256) sEP[o] = W1[o] + b1[o & 127];
  __syncthreads();

  // ---- A[i][j] = sum_r adj[r][i][j]*deg[r][i] (stride-1 writes, no conflicts) ----
  for (int o = tid; o < NN*NN; o += 256) {
    const int i = o / NN, j = o - i*NN;
    const float v = adjB[i*NN + j]          * sDeg[i]
                  + adjB[(NN + i)*NN + j]   * sDeg[NN + i]
                  + adjB[(2*NN + i)*NN + j] * sDeg[2*NN + i];
    sA[i*49 + j] = v;
  }
  __syncthreads();

  // ---- M1: h = tanh(A@h1 + h1), h1[k] = embT[node_k]. Tile 6i x 4d. ----
  {
    const int i0 = (tid >> 5)*6, d0 = (tid & 31)*4;
    float acc[6][4] = {};
    #pragma unroll 4
    for (int k = 0; k < NN; ++k) {
      const int nk = sNi[k];
      const float4 bv = *(const float4*)&sEP[nk*128 + d0];
      const float* ap = &sA[i0*49 + k];
      #pragma unroll
      for (int ii = 0; ii < 6; ++ii) {
        const float a = ap[ii*49];
        acc[ii][0] = fmaf(a, bv.x, acc[ii][0]);
        acc[ii][1] = fmaf(a, bv.y, acc[ii][1]);
        acc[ii][2] = fmaf(a, bv.z, acc[ii][2]);
        acc[ii][3] = fmaf(a, bv.w, acc[ii][3]);
      }
    }
    #pragma unroll
    for (int ii = 0; ii < 6; ++ii) {
      const float4 rv = *(const float4*)&sEP[sNi[i0+ii]*128 + d0];
      float4 o;
      o.x = tanhf(acc[ii][0] + rv.x);
      o.y = tanhf(acc[ii][1] + rv.y);
      o.z = tanhf(acc[ii][2] + rv.z);
      o.w = tanhf(acc[ii][3] + rv.w);
      *(float4*)&sH[(i0+ii)*132 + d0] = o;
    }
  }
  __syncthreads();

  const int i2 = (tid >> 4)*3, d2 = (tid & 15)*4;

  // ---- M2: h2 = h@W2 + b2 (48x64, K=128). B from global (L1/L2-hot). ----
  {
    float acc[3][4] = {};
    #pragma unroll 8
    for (int k = 0; k < 128; ++k) {
      const float4 bv = *(const float4*)&W2[k*64 + d2];
      const float* ap = &sH[i2*132 + k];
      #pragma unroll
      for (int ii = 0; ii < 3; ++ii) {
        const float a = ap[ii*132];
        acc[ii][0] = fmaf(a, bv.x, acc[ii][0]);
        acc[ii][1] = fmaf(a, bv.y, acc[ii][1]);
        acc[ii][2] = fmaf(a, bv.z, acc[ii][2]);
        acc[ii][3] = fmaf(a, bv.w, acc[ii][3]);
      }
    }
    const float4 bb = *(const float4*)&b2[d2];
    #pragma unroll
    for (int ii = 0; ii < 3; ++ii) {
      float4 o;
      o.x = acc[ii][0] + bb.x; o.y = acc[ii][1] + bb.y;
      o.z = acc[ii][2] + bb.z; o.w = acc[ii][3] + bb.w;
      *(float4*)&sH2[(i2+ii)*68 + d2] = o;
    }
  }
  __syncthreads();

  // ---- M3: h_out = tanh(A@h2 + h2) (48x64, K=48). Overwrites sH. ----
  {
    float acc[3][4] = {};
    #pragma unroll 4
    for (int k = 0; k < NN; ++k) {
      const float4 bv = *(const float4*)&sH2[k*68 + d2];
      const float* ap = &sA[i2*49 + k];
      #pragma unroll
      for (int ii = 0; ii < 3; ++ii) {
        const float a = ap[ii*49];
        acc[ii][0] = fmaf(a, bv.x, acc[ii][0]);
        acc[ii][1] = fmaf(a, bv.y, acc[ii][1]);
        acc[ii][2] = fmaf(a, bv.z, acc[ii][2]);
        acc[ii][3] = fmaf(a, bv.w, acc[ii][3]);
      }
    }
    float4 o[3];
    #pragma unroll
    for (int ii = 0; ii < 3; ++ii) {
      const float4 rv = *(const float4*)&sH2[(i2+ii)*68 + d2];
      o[ii].x = tanhf(acc[ii][0] + rv.x);
      o[ii].y = tanhf(acc[ii][1] + rv.y);
      o[ii].z = tanhf(acc[ii][2] + rv.z);
      o[ii].w = tanhf(acc[ii][3] + rv.w);
    }
    #pragma unroll
    for (int ii = 0; ii < 3; ++ii)
      *(float4*)&sH[(i2+ii)*132 + d2] = o[ii];
  }
  __syncthreads();   // sH (h_out) visible; sH2 (h2) now dead

  // ---- stage agg onehot-gather rows + biases into sH2 ----
  for (int o = tid; o < 1152; o += 256) sH2[o]        = agg_sW[(64 + (o>>7))*128 + (o&127)];
  for (int o = tid; o < 1152; o += 256) sH2[1152 + o] = agg_tW[(64 + (o>>7))*128 + (o&127)];
  if (tid < 128) sH2[2304 + tid] = agg_sb[tid];
  else if (tid < 256) sH2[2432 + (tid-128)] = agg_tb[tid-128];
  __syncthreads();

  // ---- M4: gate = sigmoid(.)*tanh(.), summed over i (deterministic, libm) ----
  for (int ch = 0; ch < 2; ++ch) {
    float as[3][4] = {}, at[3][4] = {};
    const float* sWp = agg_sW + ch*64 + d2;
    const float* tWp = agg_tW + ch*64 + d2;
    #pragma unroll 4
    for (int k = 0; k < 64; ++k) {
      const float4 bs = *(const float4*)&sWp[k*128];
      const float4 bt = *(const float4*)&tWp[k*128];
      const float* ap = &sH[i2*132 + k];
      #pragma unroll
      for (int ii = 0; ii < 3; ++ii) {
        const float a = ap[ii*132];
        as[ii][0] = fmaf(a, bs.x, as[ii][0]);
        as[ii][1] = fmaf(a, bs.y, as[ii][1]);
        as[ii][2] = fmaf(a, bs.z, as[ii][2]);
        as[ii][3] = fmaf(a, bs.w, as[ii][3]);
        at[ii][0] = fmaf(a, bt.x, at[ii][0]);
        at[ii][1] = fmaf(a, bt.y, at[ii][1]);
        at[ii][2] = fmaf(a, bt.z, at[ii][2]);
        at[ii][3] = fmaf(a, bt.w, at[ii][3]);
      }
    }
    float part[4] = {0.f, 0.f, 0.f, 0.f};
    const float* bsb = &sH2[2304 + ch*64 + d2];
    const float* btb = &sH2[2432 + ch*64 + d2];
    #pragma unroll
    for (int ii = 0; ii < 3; ++ii) {
      const int t = sNi[i2+ii];
      const float* gsp = &sH2[t*128 + ch*64 + d2];
      const float* gtp = &sH2[1152 + t*128 + ch*64 + d2];
      #pragma unroll
      for (int dd = 0; dd < 4; ++dd) {
        const float sgm = 1.0f/(1.0f + expf(-(as[ii][dd] + gsp[dd] + bsb[dd])));
        const float tg  = tanhf(at[ii][dd] + gtp[dd] + btb[dd]);
        part[dd] = fmaf(sgm, tg, part[dd]);
      }
    }
    const int grp = tid >> 4;
    *(float4*)&sEP[grp*64 + d2] = *(float4*)part;
    __syncthreads();
    if (tid < 64) {
      float s = 0.0f;
      #pragma unroll
      for (int g = 0; g < 16; ++g) s += sEP[g*64 + tid];
      sGsum[ch*64 + tid] = s;
    }
    __syncthreads();
  }

  // ---- tail MLP (tiny, per item); sT lives in sH2[2560..3177) ----
  float* sT = &sH2[2560];
  if (tid < 128) sT[tid] = tanhf(sGsum[tid]);          // g: [0..128)
  __syncthreads();
  if (tid < 128) {                                     // a1: [128..256)
    float a = l1b[tid];
    for (int k = 0; k < 128; ++k) a = fmaf(sT[k], l1W[k*128 + tid], a);
    sT[128 + tid] = a;
  }
  __syncthreads();
  if (tid < 64) {                                      // hfeat: [256..320)
    float a = l2b[tid];
    for (int k = 0; k < 128; ++k) a = fmaf(sT[128+k], l2W[k*64 + tid], a);
    sT[256 + tid] = a;
  }
  __syncthreads();
  if (tid < 160) {                                     // 5 heads L1: [320..480)
    const int hh = tid >> 5, j = tid & 31;
    const float* Wp = (hh==0) ? f1 : (hh==1) ? s1 : (hh==2) ? e1 : (hh==3) ? t1W : v1W;
    float a = (hh==3) ? t1b[j] : (hh==4) ? v1b[j] : 0.0f;
    for (int k = 0; k < 64; ++k) a = fmaf(sT[256+k], Wp[k*32 + j], a);
    sT[320 + tid] = (a > 0.0f) ? a : 0.1f*a;
  }
  __syncthreads();
  if (tid < 56) {                                      // out1: [480..536)
    float a = 0.0f;
    for (int k = 0; k < 32; ++k) a = fmaf(sT[320+k], f2[k*56 + tid], a);
    sT[480 + tid] = a;
  } else if (tid < 112) {                              // out2: [536..592)
    const int m = tid - 56; float a = 0.0f;
    for (int k = 0; k < 32; ++k) a = fmaf(sT[352+k], s2[k*56 + m], a);
    sT[536 + m] = a;
  } else if (tid < 115) {                              // oute: [592..595)
    const int m = tid - 112; float a = 0.0f;
    for (int k = 0; k < 32; ++k) a = fmaf(sT[384+k], e2[k*3 + m], a);
    sT[592 + m] = a;
  } else if (tid < 117) {                              // outs: [595..597)
    const int m = tid - 115; float a = t2b[m];
    for (int k = 0; k < 32; ++k) a = fmaf(sT[416+k], t2W[k*2 + m], a);
    sT[595 + m] = a;
  } else if (tid < 133) {                              // v2h: [600..616)
    const int m = tid - 117; float a = v2b[m];
    for (int k = 0; k < 32; ++k) a = fmaf(sT[448+k], v2W[k*16 + m], a);
    sT[600 + m] = (a > 0.0f) ? a : 0.1f*a;
  }
  __syncthreads();
  if (tid == 0) {                                      // value: [616]
    float a = v3b[0];
    for (int k = 0; k < 16; ++k) a = fmaf(sT[600+k], v3W[k], a);
    sT[616] = a;
  }
  __syncthreads();

  // ---- masks + softmaxes, wave 0 (post-argmax: fast math OK) ----
  if (tid < 64) {
    const int m = tid;
    const bool inb = (m < MD);
    const bool ex  = inb && (sNi[m] > 0) && (m < NN);
    const size_t ob = (size_t)b * 118;

    float lg1 = inb ? (sT[480+m] + (ex ? 0.0f : -10000.0f)) : -INFINITY;
    float mv = lg1; int mi = inb ? m : 1000;
    #pragma unroll
    for (int off = 32; off > 0; off >>= 1) {
      const float ov = __shfl_down(mv, off);
      const int   oi = __shfl_down(mi, off);
      if (ov > mv || (ov == mv && oi < mi)) { mv = ov; mi = oi; }
    }
    mv = __shfl(mv, 0);
    const int first = __shfl(mi, 0);
    float ev = inb ? __expf(lg1 - mv) : 0.0f;
    float sum1 = ev;
    #pragma unroll
    for (int off = 32; off > 0; off >>= 1) sum1 += __shfl_down(sum1, off);
    sum1 = rcp_f(__shfl(sum1, 0));
    if (inb) out[ob + m] = ev * sum1;

    const bool m2 = inb && ((ex || m >= NN) && (m != first));
    float lg2 = inb ? (sT[536+m] + (m2 ? 0.0f : -10000.0f)) : -INFINITY;
    float mv2 = lg2;
    #pragma unroll
    for (int off = 32; off > 0; off >>= 1) mv2 = fmaxf(mv2, __shfl_down(mv2, off));
    mv2 = __shfl(mv2, 0);
    float ev2 = inb ? __expf(lg2 - mv2) : 0.0f;
    float sum2 = ev2;
    #pragma unroll
    for (int off = 32; off > 0; off >>= 1) sum2 += __shfl_down(sum2, off);
    sum2 = rcp_f(__shfl(sum2, 0));
    if (inb) out[ob + 56 + m] = ev2 * sum2;

    if (m < 3) {
      const float x0 = sT[592], x1 = sT[593], x2 = sT[594];
      const float mx = fmaxf(x0, fmaxf(x1, x2));
      const float q0 = __expf(x0-mx), q1 = __expf(x1-mx), q2 = __expf(x2-mx);
      out[ob + 112 + m] = ((m==0) ? q0 : (m==1) ? q1 : q2) / (q0+q1+q2);
    }
    if (m < 2) {
      const float x0 = sT[595], x1 = sT[596];
      const float mx = fmaxf(x0, x1);
      const float q0 = __expf(x0-mx), q1 = __expf(x1-mx);
      out[ob + 115 + m] = ((m==0) ? q0 : q1) / (q0+q1);
    }
    if (m == 0) out[ob + 117] = sT[616];
  }
}

extern "C" void kernel_launch(void* const* d_in, const int* in_sizes, int n_in,
                              void* d_out, int out_size, void* d_ws, size_t ws_size,
                              hipStream_t stream) {
  (void)n_in; (void)out_size; (void)d_ws; (void)ws_size;
  const int B = in_sizes[0] / MD;
  policy_fwd<<<dim3(B), dim3(256), 0, stream>>>(
      (const int*)d_in[0],  (const float*)d_in[1],
      (const float*)d_in[2],  (const float*)d_in[3],
      (const float*)d_in[4],  (const float*)d_in[5],
      (const float*)d_in[6],  (const float*)d_in[7],
      (const float*)d_in[8],  (const float*)d_in[9],
      (const float*)d_in[10], (const float*)d_in[11],
      (const float*)d_in[12], (const float*)d_in[13],
      (const float*)d_in[14], (const float*)d_in[15],
      (const float*)d_in[16], (const float*)d_in[17],
      (const float*)d_in[18], (const float*)d_in[19],
      (const float*)d_in[20], (const float*)d_in[21],
      (const float*)d_in[22], (const float*)d_in[23],
      (const float*)d_in[24], (const float*)d_in[25],
      (const float*)d_in[26], (const float*)d_in[27],
      (const float*)d_in[28], (const float*)d_in[29],
      (float*)d_out);
}

// Round 5
// 922.422 us; speedup vs baseline: 2.3467x; 1.0242x over previous
//
#include <hip/hip_runtime.h>
#include <math.h>

#define NN 48
#define MD 56

__device__ __forceinline__ float rcp_f(float x){
#if __has_builtin(__builtin_amdgcn_rcpf)
  return __builtin_amdgcn_rcpf(x);
#else
  return 1.0f/x;
#endif
}

// One block per batch item; 256 threads.
// LDS 40672 B <= 40960 -> 4 blocks/CU (16 waves). Math chains bit-identical to R4.
__global__ __launch_bounds__(256, 4)
void policy_fwd(const int* __restrict__ Nmat, const float* __restrict__ adj,
                const float* __restrict__ W1, const float* __restrict__ b1,
                const float* __restrict__ W2, const float* __restrict__ b2,
                const float* __restrict__ agg_sW, const float* __restrict__ agg_sb,
                const float* __restrict__ agg_tW, const float* __restrict__ agg_tb,
                const float* __restrict__ l1W, const float* __restrict__ l1b,
                const float* __restrict__ l2W, const float* __restrict__ l2b,
                const float* __restrict__ f1, const float* __restrict__ f2,
                const float* __restrict__ s1, const float* __restrict__ s2,
                const float* __restrict__ e1, const float* __restrict__ e2,
                const float* __restrict__ t1W, const float* __restrict__ t1b,
                const float* __restrict__ t2W, const float* __restrict__ t2b,
                const float* __restrict__ v1W, const float* __restrict__ v1b,
                const float* __restrict__ v2W, const float* __restrict__ v2b,
                const float* __restrict__ v3W, const float* __restrict__ v3b,
                float* __restrict__ out)
{
  __shared__ __align__(16) float sA[NN*48];    // A row-major, stride 48 (reads are broadcast)
  __shared__ __align__(16) float sHB[3264];    // h col-block / h_out / tail sT; deg in [3104..3248)
  __shared__ __align__(16) float sH2[3264];    // h2 (48x68); later M4 ch1 partials
  __shared__ __align__(16) float sEP[1280];    // embT[9][128]; later ch0 partials[16][64] + gsum[128]
  __shared__ int   sNi[MD];

  const int b   = blockIdx.x;
  const int tid = threadIdx.x;
  const float* adjB = adj + (size_t)b * (3*NN*NN);
  float* sDeg = &sHB[3104];

  if (tid < MD) sNi[tid] = Nmat[b*MD + tid];

  // ---- degrees: deg[r][i] = 1/(1+row_sum); 16 lanes per row (exact div) ----
  {
    const int lane = tid & 15, grp = tid >> 4;
    for (int p = 0; p < 9; ++p) {
      const int row = p*16 + grp;               // r*48+i
      const float* rp = adjB + row*NN;
      float s = rp[lane] + rp[lane+16] + rp[lane+32];
      s += __shfl_down(s, 8, 16);
      s += __shfl_down(s, 4, 16);
      s += __shfl_down(s, 2, 16);
      s += __shfl_down(s, 1, 16);
      if (lane == 0) sDeg[row] = 1.0f/(s + 1.0f);
    }
  }
  // embT[t][d] = W1[t][d] + b1[d]  (9x128)
  for (int o = tid; o < 1152; o += 256) sEP[o] = W1[o] + b1[o & 127];
  __syncthreads();

  // ---- A[i][j] = sum_r adj[r][i][j]*deg[r][i] (stride-1 writes) ----
  for (int o = tid; o < NN*NN; o += 256) {
    const int i = o / NN, j = o - i*NN;
    const float v = adjB[i*NN + j]          * sDeg[i]
                  + adjB[(NN + i)*NN + j]   * sDeg[NN + i]
                  + adjB[(2*NN + i)*NN + j] * sDeg[2*NN + i];
    sA[i*48 + j] = v;
  }
  __syncthreads();   // sA ready; sHB (deg region) dead after this

  const int i2 = (tid >> 4)*3, d2 = (tid & 15)*4;

  // ---- M1+M2 fused in two 64-column rounds.
  // h[:,blk] -> sHB, consumed into persistent acc2; per-element chains
  // identical to unfused (k sequential 0..47 for h; 0..127 for h2).
  float acc2[3][4] = {};
  #pragma unroll
  for (int r = 0; r < 2; ++r) {
    const int dg = r*64 + d2;   // global d in [0,128)
    // M1: h(i2..i2+2, dg..dg+3)
    {
      float acc[3][4] = {};
      #pragma unroll 4
      for (int k = 0; k < NN; ++k) {
        const int nk = sNi[k];
        const float4 bv = *(const float4*)&sEP[nk*128 + dg];
        const float* ap = &sA[i2*48 + k];
        #pragma unroll
        for (int ii = 0; ii < 3; ++ii) {
          const float a = ap[ii*48];
          acc[ii][0] = fmaf(a, bv.x, acc[ii][0]);
          acc[ii][1] = fmaf(a, bv.y, acc[ii][1]);
          acc[ii][2] = fmaf(a, bv.z, acc[ii][2]);
          acc[ii][3] = fmaf(a, bv.w, acc[ii][3]);
        }
      }
      #pragma unroll
      for (int ii = 0; ii < 3; ++ii) {
        const float4 rv = *(const float4*)&sEP[sNi[i2+ii]*128 + dg];
        float4 o;
        o.x = tanhf(acc[ii][0] + rv.x);
        o.y = tanhf(acc[ii][1] + rv.y);
        o.z = tanhf(acc[ii][2] + rv.z);
        o.w = tanhf(acc[ii][3] + rv.w);
        *(float4*)&sHB[(i2+ii)*68 + d2] = o;
      }
    }
    __syncthreads();   // h block visible
    // M2 accumulate: h2 += h[:,blk] @ W2[blk,:]
    {
      const float* W2r = W2 + (size_t)r*64*64;
      #pragma unroll 8
      for (int k = 0; k < 64; ++k) {
        const float4 bv = *(const float4*)&W2r[k*64 + d2];
        const float* ap = &sHB[i2*68 + k];
        #pragma unroll
        for (int ii = 0; ii < 3; ++ii) {
          const float a = ap[ii*68];
          acc2[ii][0] = fmaf(a, bv.x, acc2[ii][0]);
          acc2[ii][1] = fmaf(a, bv.y, acc2[ii][1]);
          acc2[ii][2] = fmaf(a, bv.z, acc2[ii][2]);
          acc2[ii][3] = fmaf(a, bv.w, acc2[ii][3]);
        }
      }
    }
    __syncthreads();   // all reads of sHB done before next round overwrites
  }
  // h2 = acc2 + b2 -> sH2
  {
    const float4 bb = *(const float4*)&b2[d2];
    #pragma unroll
    for (int ii = 0; ii < 3; ++ii) {
      float4 o;
      o.x = acc2[ii][0] + bb.x; o.y = acc2[ii][1] + bb.y;
      o.z = acc2[ii][2] + bb.z; o.w = acc2[ii][3] + bb.w;
      *(float4*)&sH2[(i2+ii)*68 + d2] = o;
    }
  }
  __syncthreads();

  // ---- M3: h_out = tanh(A@h2 + h2) (48x64, K=48) -> sHB ----
  {
    float acc[3][4] = {};
    #pragma unroll 4
    for (int k = 0; k < NN; ++k) {
      const float4 bv = *(const float4*)&sH2[k*68 + d2];
      const float* ap = &sA[i2*48 + k];
      #pragma unroll
      for (int ii = 0; ii < 3; ++ii) {
        const float a = ap[ii*48];
        acc[ii][0] = fmaf(a, bv.x, acc[ii][0]);
        acc[ii][1] = fmaf(a, bv.y, acc[ii][1]);
        acc[ii][2] = fmaf(a, bv.z, acc[ii][2]);
        acc[ii][3] = fmaf(a, bv.w, acc[ii][3]);
      }
    }
    #pragma unroll
    for (int ii = 0; ii < 3; ++ii) {
      const float4 rv = *(const float4*)&sH2[(i2+ii)*68 + d2];
      float4 o;
      o.x = tanhf(acc[ii][0] + rv.x);
      o.y = tanhf(acc[ii][1] + rv.y);
      o.z = tanhf(acc[ii][2] + rv.z);
      o.w = tanhf(acc[ii][3] + rv.w);
      *(float4*)&sHB[(i2+ii)*68 + d2] = o;
    }
  }
  __syncthreads();   // h_out visible; sH2 (h2) dead; sEP (emb) dead

  // ---- M4: both channels in ONE k-pass (chains identical to per-ch runs).
  {
    float as0[3][4] = {}, as1[3][4] = {}, at0[3][4] = {}, at1[3][4] = {};
    #pragma unroll 4
    for (int k = 0; k < 64; ++k) {
      const float4 bs0 = *(const float4*)&agg_sW[k*128 + d2];
      const float4 bs1 = *(const float4*)&agg_sW[k*128 + 64 + d2];
      const float4 bt0 = *(const float4*)&agg_tW[k*128 + d2];
      const float4 bt1 = *(const float4*)&agg_tW[k*128 + 64 + d2];
      const float* ap = &sHB[i2*68 + k];
      #pragma unroll
      for (int ii = 0; ii < 3; ++ii) {
        const float a = ap[ii*68];
        as0[ii][0] = fmaf(a, bs0.x, as0[ii][0]);
        as0[ii][1] = fmaf(a, bs0.y, as0[ii][1]);
        as0[ii][2] = fmaf(a, bs0.z, as0[ii][2]);
        as0[ii][3] = fmaf(a, bs0.w, as0[ii][3]);
        as1[ii][0] = fmaf(a, bs1.x, as1[ii][0]);
        as1[ii][1] = fmaf(a, bs1.y, as1[ii][1]);
        as1[ii][2] = fmaf(a, bs1.z, as1[ii][2]);
        as1[ii][3] = fmaf(a, bs1.w, as1[ii][3]);
        at0[ii][0] = fmaf(a, bt0.x, at0[ii][0]);
        at0[ii][1] = fmaf(a, bt0.y, at0[ii][1]);
        at0[ii][2] = fmaf(a, bt0.z, at0[ii][2]);
        at0[ii][3] = fmaf(a, bt0.w, at0[ii][3]);
        at1[ii][0] = fmaf(a, bt1.x, at1[ii][0]);
        at1[ii][1] = fmaf(a, bt1.y, at1[ii][1]);
        at1[ii][2] = fmaf(a, bt1.z, at1[ii][2]);
        at1[ii][3] = fmaf(a, bt1.w, at1[ii][3]);
      }
    }
    // epilogue: onehot-gather rows + biases straight from global (L2-hot);
    // add order matches R4: acc + gather + bias.
    float p0[4] = {0.f,0.f,0.f,0.f}, p1[4] = {0.f,0.f,0.f,0.f};
    const float4 bsb0 = *(const float4*)&agg_sb[d2];
    const float4 bsb1 = *(const float4*)&agg_sb[64 + d2];
    const float4 btb0 = *(const float4*)&agg_tb[d2];
    const float4 btb1 = *(const float4*)&agg_tb[64 + d2];
    const float bsb0a[4] = {bsb0.x,bsb0.y,bsb0.z,bsb0.w};
    const float bsb1a[4] = {bsb1.x,bsb1.y,bsb1.z,bsb1.w};
    const float btb0a[4] = {btb0.x,btb0.y,btb0.z,btb0.w};
    const float btb1a[4] = {btb1.x,btb1.y,btb1.z,btb1.w};
    #pragma unroll
    for (int ii = 0; ii < 3; ++ii) {
      const int t = sNi[i2+ii];
      const float* gs = &agg_sW[(64 + t)*128];
      const float* gt = &agg_tW[(64 + t)*128];
      #pragma unroll
      for (int dd = 0; dd < 4; ++dd) {
        const float sg0 = 1.0f/(1.0f + expf(-(as0[ii][dd] + gs[d2+dd]      + bsb0a[dd])));
        const float tg0 = tanhf(at0[ii][dd] + gt[d2+dd]      + btb0a[dd]);
        p0[dd] = fmaf(sg0, tg0, p0[dd]);
        const float sg1 = 1.0f/(1.0f + expf(-(as1[ii][dd] + gs[64+d2+dd] + bsb1a[dd])));
        const float tg1 = tanhf(at1[ii][dd] + gt[64+d2+dd] + btb1a[dd]);
        p1[dd] = fmaf(sg1, tg1, p1[dd]);
      }
    }
    const int grp = tid >> 4;
    *(float4*)&sEP[grp*64 + d2] = *(float4*)p0;   // ch0 partials (emb dead)
    *(float4*)&sH2[grp*64 + d2] = *(float4*)p1;   // ch1 partials (h2 dead)
  }
  __syncthreads();
  if (tid < 64) {                      // fixed-order 16-group sums (as R4)
    float s = 0.0f;
    #pragma unroll
    for (int g = 0; g < 16; ++g) s += sEP[g*64 + tid];
    sEP[1024 + tid] = s;               // gsum ch0
  } else if (tid < 128) {
    const int m = tid - 64;
    float s = 0.0f;
    #pragma unroll
    for (int g = 0; g < 16; ++g) s += sH2[g*64 + m];
    sEP[1024 + 64 + m] = s;            // gsum ch1
  }
  __syncthreads();

  // ---- tail MLP; sT lives in sHB (h_out dead after M4) ----
  float* sT = sHB;
  const float* sGsum = &sEP[1024];
  if (tid < 128) sT[tid + 1024] = tanhf(sGsum[tid]);   // g: sT[1024..1152) (avoid aliasing h_out reads? h_out fully dead)
  __syncthreads();
  if (tid < 128) {                                     // a1: sT[1152..1280)
    float a = l1b[tid];
    for (int k = 0; k < 128; ++k) a = fmaf(sT[1024+k], l1W[k*128 + tid], a);
    sT[1152 + tid] = a;
  }
  __syncthreads();
  if (tid < 64) {                                      // hfeat: sT[1280..1344)
    float a = l2b[tid];
    for (int k = 0; k < 128; ++k) a = fmaf(sT[1152+k], l2W[k*64 + tid], a);
    sT[1280 + tid] = a;
  }
  __syncthreads();
  if (tid < 160) {                                     // 5 heads L1: sT[1344..1504)
    const int hh = tid >> 5, j = tid & 31;
    const float* Wp = (hh==0) ? f1 : (hh==1) ? s1 : (hh==2) ? e1 : (hh==3) ? t1W : v1W;
    float a = (hh==3) ? t1b[j] : (hh==4) ? v1b[j] : 0.0f;
    for (int k = 0; k < 64; ++k) a = fmaf(sT[1280+k], Wp[k*32 + j], a);
    sT[1344 + tid] = (a > 0.0f) ? a : 0.1f*a;
  }
  __syncthreads();
  if (tid < 56) {                                      // out1: sT[1504..1560)
    float a = 0.0f;
    for (int k = 0; k < 32; ++k) a = fmaf(sT[1344+k], f2[k*56 + tid], a);
    sT[1504 + tid] = a;
  } else if (tid < 112) {                              // out2: sT[1560..1616)
    const int m = tid - 56; float a = 0.0f;
    for (int k = 0; k < 32; ++k) a = fmaf(sT[1376+k], s2[k*56 + m], a);
    sT[1560 + m] = a;
  } else if (tid < 115) {                              // oute: sT[1616..1619)
    const int m = tid - 112; float a = 0.0f;
    for (int k = 0; k < 32; ++k) a = fmaf(sT[1408+k], e2[k*3 + m], a);
    sT[1616 + m] = a;
  } else if (tid < 117) {                              // outs: sT[1619..1621)
    const int m = tid - 115; float a = t2b[m];
    for (int k = 0; k < 32; ++k) a = fmaf(sT[1440+k], t2W[k*2 + m], a);
    sT[1619 + m] = a;
  } else if (tid < 133) {                              // v2h: sT[1624..1640)
    const int m = tid - 117; float a = v2b[m];
    for (int k = 0; k < 32; ++k) a = fmaf(sT[1472+k], v2W[k*16 + m], a);
    sT[1624 + m] = (a > 0.0f) ? a : 0.1f*a;
  }
  __syncthreads();
  if (tid == 0) {                                      // value: sT[1640]
    float a = v3b[0];
    for (int k = 0; k < 16; ++k) a = fmaf(sT[1624+k], v3W[k], a);
    sT[1640] = a;
  }
  __syncthreads();

  // ---- masks + softmaxes, wave 0 (post-argmax: fast math OK) ----
  if (tid < 64) {
    const int m = tid;
    const bool inb = (m < MD);
    const bool ex  = inb && (sNi[m] > 0) && (m < NN);
    const size_t ob = (size_t)b * 118;

    float lg1 = inb ? (sT[1504+m] + (ex ? 0.0f : -10000.0f)) : -INFINITY;
    float mv = lg1; int mi = inb ? m : 1000;
    #pragma unroll
    for (int off = 32; off > 0; off >>= 1) {
      const float ov = __shfl_down(mv, off);
      const int   oi = __shfl_down(mi, off);
      if (ov > mv || (ov == mv && oi < mi)) { mv = ov; mi = oi; }
    }
    mv = __shfl(mv, 0);
    const int first = __shfl(mi, 0);
    float ev = inb ? __expf(lg1 - mv) : 0.0f;
    float sum1 = ev;
    #pragma unroll
    for (int off = 32; off > 0; off >>= 1) sum1 += __shfl_down(sum1, off);
    sum1 = rcp_f(__shfl(sum1, 0));
    if (inb) out[ob + m] = ev * sum1;

    const bool m2 = inb && ((ex || m >= NN) && (m != first));
    float lg2 = inb ? (sT[1560+m] + (m2 ? 0.0f : -10000.0f)) : -INFINITY;
    float mv2 = lg2;
    #pragma unroll
    for (int off = 32; off > 0; off >>= 1) mv2 = fmaxf(mv2, __shfl_down(mv2, off));
    mv2 = __shfl(mv2, 0);
    float ev2 = inb ? __expf(lg2 - mv2) : 0.0f;
    float sum2 = ev2;
    #pragma unroll
    for (int off = 32; off > 0; off >>= 1) sum2 += __shfl_down(sum2, off);
    sum2 = rcp_f(__shfl(sum2, 0));
    if (inb) out[ob + 56 + m] = ev2 * sum2;

    if (m < 3) {
      const float x0 = sT[1616], x1 = sT[1617], x2 = sT[1618];
      const float mx = fmaxf(x0, fmaxf(x1, x2));
      const float q0 = __expf(x0-mx), q1 = __expf(x1-mx), q2 = __expf(x2-mx);
      out[ob + 112 + m] = ((m==0) ? q0 : (m==1) ? q1 : q2) / (q0+q1+q2);
    }
    if (m < 2) {
      const float x0 = sT[1619], x1 = sT[1620];
      const float mx = fmaxf(x0, x1);
      const float q0 = __expf(x0-mx), q1 = __expf(x1-mx);
      out[ob + 115 + m] = ((m==0) ? q0 : q1) / (q0+q1);
    }
    if (m == 0) out[ob + 117] = sT[1640];
  }
}

extern "C" void kernel_launch(void* const* d_in, const int* in_sizes, int n_in,
                              void* d_out, int out_size, void* d_ws, size_t ws_size,
                              hipStream_t stream) {
  (void)n_in; (void)out_size; (void)d_ws; (void)ws_size;
  const int B = in_sizes[0] / MD;
  policy_fwd<<<dim3(B), dim3(256), 0, stream>>>(
      (const int*)d_in[0],  (const float*)d_in[1],
      (const float*)d_in[2],  (const float*)d_in[3],
      (const float*)d_in[4],  (const float*)d_in[5],
      (const float*)d_in[6],  (const float*)d_in[7],
      (const float*)d_in[8],  (const float*)d_in[9],
      (const float*)d_in[10], (const float*)d_in[11],
      (const float*)d_in[12], (const float*)d_in[13],
      (const float*)d_in[14], (const float*)d_in[15],
      (const float*)d_in[16], (const float*)d_in[17],
      (const float*)d_in[18], (const float*)d_in[19],
      (const float*)d_in[20], (const float*)d_in[21],
      (const float*)d_in[22], (const float*)d_in[23],
      (const float*)d_in[24], (const float*)d_in[25],
      (const float*)d_in[26], (const float*)d_in[27],
      (const float*)d_in[28], (const float*)d_in[29],
      (float*)d_out);
}